// Round 5
// baseline (242.514 us; speedup 1.0000x reference)
//
#include <hip/hip_runtime.h>
#include <hip/hip_bf16.h>
#include <cstdint>
#include <cstddef>

#define BB 4
#define TT 4096
#define HH 16
#define NROWS 16384  // B*T

typedef __attribute__((ext_vector_type(8))) short bf16x8;
typedef __attribute__((ext_vector_type(4))) float f32x4;

__device__ __forceinline__ void gload_lds16(const void* g, void* l) {
  __builtin_amdgcn_global_load_lds(
      (const __attribute__((address_space(1))) void*)g,
      (__attribute__((address_space(3))) void*)l, 16, 0, 0);
}

template <int N>
__device__ __forceinline__ void wait_vmcnt() {
  if constexpr (N == 8)
    asm volatile("s_waitcnt vmcnt(8)" ::: "memory");
  else if constexpr (N == 4)
    asm volatile("s_waitcnt vmcnt(4)" ::: "memory");
  else
    asm volatile("s_waitcnt vmcnt(0)" ::: "memory");
  __builtin_amdgcn_sched_barrier(0);
}

__device__ __forceinline__ void hbar() {
  asm volatile("s_barrier" ::: "memory");
  __builtin_amdgcn_sched_barrier(0);
}

// ---------------------------------------------------------------------------
// x (f32) -> bf16, 8 elems/thread
// ---------------------------------------------------------------------------
__global__ __launch_bounds__(256) void xconv_k(const float* __restrict__ x,
                                               __hip_bfloat16* __restrict__ xb) {
  const size_t i = ((size_t)blockIdx.x * 256 + threadIdx.x) * 8;
  float4 a = *(const float4*)&x[i];
  float4 b = *(const float4*)&x[i + 4];
  __hip_bfloat16 o[8] __attribute__((aligned(16)));
  o[0] = __float2bfloat16(a.x); o[1] = __float2bfloat16(a.y);
  o[2] = __float2bfloat16(a.z); o[3] = __float2bfloat16(a.w);
  o[4] = __float2bfloat16(b.x); o[5] = __float2bfloat16(b.y);
  o[6] = __float2bfloat16(b.z); o[7] = __float2bfloat16(b.w);
  *(int4*)&xb[i] = *(const int4*)o;
}

// ---------------------------------------------------------------------------
// W [1024][1024] f32 -> WT bf16 transposed; 4 matrices packed.
// ---------------------------------------------------------------------------
__global__ __launch_bounds__(256) void wconv_k(const float* __restrict__ Wq,
                                               const float* __restrict__ Wk,
                                               const float* __restrict__ Wv,
                                               const float* __restrict__ Wo,
                                               __hip_bfloat16* __restrict__ WT) {
  const int which = blockIdx.z;
  const float* W = which == 0 ? Wq : which == 1 ? Wk : which == 2 ? Wv : Wo;
  __shared__ float tile[64][65];
  const int n0 = blockIdx.x * 64, k0 = blockIdx.y * 64;
  const int t = threadIdx.x;
  const int r = t >> 2;
  const int cq = (t & 3) * 16;
#pragma unroll
  for (int i = 0; i < 4; ++i) {
    float4 v = *(const float4*)&W[(size_t)(k0 + r) * 1024 + n0 + cq + i * 4];
    tile[r][cq + i * 4 + 0] = v.x;
    tile[r][cq + i * 4 + 1] = v.y;
    tile[r][cq + i * 4 + 2] = v.z;
    tile[r][cq + i * 4 + 3] = v.w;
  }
  __syncthreads();
  __hip_bfloat16 ob[16] __attribute__((aligned(16)));
#pragma unroll
  for (int j = 0; j < 16; ++j) ob[j] = __float2bfloat16(tile[cq + j][r]);
  __hip_bfloat16* dst = WT + (size_t)(which * 1024 + n0 + r) * 1024 + k0 + cq;
  *(int4*)dst = *(const int4*)&ob[0];
  *(int4*)(dst + 8) = *(const int4*)&ob[8];
}

// ---------------------------------------------------------------------------
// MFMA bf16 GEMM, 256x256 tile, BK=32, ring-4 LDS, counted vmcnt.
// 512 threads = 8 waves (2M x 4N); per-wave output 128x64.
//
// LDS layout (per 16-row block of each tile half): granule g (16B) holds
// row (blk*16 + (g&15)), k-quad (g>>4). Achieved by permuting the staging
// lane map (srow=l&15, skel=(l>>4)*8) while gload_lds writes lane->granule
// linearly. Fragment reads then address granule==lane (stride-1, zero
// bank conflicts) for every A and B fragment.
// PB: B pointer advances by 1M elems per 4096-row batch (fused Wo path).
// ---------------------------------------------------------------------------
template <int OMODE, int PB>
__global__ __launch_bounds__(512) void mgemm2_k(
    const __hip_bfloat16* __restrict__ A, int lda,
    const __hip_bfloat16* __restrict__ BT, const float* __restrict__ bias,
    void* __restrict__ Cp, int ldc, int gx) {
  __shared__ __hip_bfloat16 lds[4][16384];

  const int t = threadIdx.x;
  const int wid = t >> 6, l = t & 63;
  const int wr = wid >> 2, wc = wid & 3;

  const int nwg = gridDim.x;
  const int cpx = nwg >> 3;
  const int bid = blockIdx.x;
  const int swz = (bid & 7) * cpx + (bid >> 3);
  const int bx = swz % gx, by = swz / gx;
  const int row0 = by * 256, col0 = bx * 256;

  const __hip_bfloat16* BTb = PB ? BT + ((size_t)(row0 >> 12) << 20) : BT;

  // staging lane map (permuted source -> linear LDS -> linear reads)
  const int srow = l & 15, skel = (l >> 4) * 8;
  const __hip_bfloat16* Ab = A + (size_t)(row0 + wid * 16 + srow) * lda + skel;
  const __hip_bfloat16* Bb =
      BTb + (size_t)(col0 + wid * 16 + srow) * 1024 + skel;

  f32x4 acc[8][4];
#pragma unroll
  for (int m = 0; m < 8; ++m)
#pragma unroll
    for (int n = 0; n < 4; ++n) acc[m][n] = (f32x4){0.f, 0.f, 0.f, 0.f};

  const int lr = l & 15, hk = l >> 4;
  // lane-linear fragment offsets (elems): granule l of each 512-elem block
  const int aoff = wr * 4096 + hk * 128 + lr * 8;         // + m*512
  const int boff = 8192 + wc * 2048 + hk * 128 + lr * 8;  // + n*512

  auto stage = [&](int kt, int slot) {
    const int kk = kt * 32;
    __hip_bfloat16* s = &lds[slot][0];
    gload_lds16(Ab + kk, s + wid * 512);
    gload_lds16(Ab + (size_t)128 * lda + kk, s + 4096 + wid * 512);
    gload_lds16(Bb + kk, s + 8192 + wid * 512);
    gload_lds16(Bb + (size_t)128 * 1024 + kk, s + 12288 + wid * 512);
  };

  auto compute = [&](int slot) {
    const __hip_bfloat16* s = &lds[slot][0];
    bf16x8 bf[4];
#pragma unroll
    for (int n = 0; n < 4; ++n) bf[n] = *(const bf16x8*)(s + boff + n * 512);
    __builtin_amdgcn_s_setprio(1);
#pragma unroll
    for (int m = 0; m < 8; ++m) {
      bf16x8 af = *(const bf16x8*)(s + aoff + m * 512);
#pragma unroll
      for (int n = 0; n < 4; ++n)
        acc[m][n] = __builtin_amdgcn_mfma_f32_16x16x32_bf16(af, bf[n],
                                                            acc[m][n], 0, 0, 0);
    }
    __builtin_amdgcn_s_setprio(0);
  };

  stage(0, 0);
  stage(1, 1);
  stage(2, 2);
  for (int kt = 0; kt < 29; ++kt) {
    wait_vmcnt<8>();
    hbar();
    stage(kt + 3, (kt + 3) & 3);
    compute(kt & 3);
  }
  wait_vmcnt<8>(); hbar(); compute(1);
  wait_vmcnt<4>(); hbar(); compute(2);
  wait_vmcnt<0>(); hbar(); compute(3);

  const int cr = hk * 4;
  const int cc = lr;
  if constexpr (OMODE == 0) {
    __hip_bfloat16* C = (__hip_bfloat16*)Cp;
#pragma unroll
    for (int m = 0; m < 8; ++m)
#pragma unroll
      for (int n = 0; n < 4; ++n) {
        const size_t cb = (size_t)(row0 + wr * 128 + m * 16 + cr) * ldc +
                          col0 + wc * 64 + n * 16 + cc;
#pragma unroll
        for (int j = 0; j < 4; ++j)
          C[cb + (size_t)j * ldc] = __float2bfloat16(acc[m][n][j]);
      }
  } else {
    float* C = (float*)Cp;
    float bv[4];
#pragma unroll
    for (int n = 0; n < 4; ++n) bv[n] = bias[col0 + wc * 64 + n * 16 + cc];
#pragma unroll
    for (int m = 0; m < 8; ++m)
#pragma unroll
      for (int n = 0; n < 4; ++n) {
        const size_t cb = (size_t)(row0 + wr * 128 + m * 16 + cr) * ldc +
                          col0 + wc * 64 + n * 16 + cc;
#pragma unroll
        for (int j = 0; j < 4; ++j)
          C[cb + (size_t)j * ldc] = acc[m][n][j] + bv[n];
      }
  }
}

// ---------------------------------------------------------------------------
// context partials; 4d x 4e register microtile, bank-even lane mapping.
// grid (64,32) x 256
// ---------------------------------------------------------------------------
__global__ __launch_bounds__(256) void ctx_partial_k(
    const __hip_bfloat16* __restrict__ qkv, float* __restrict__ part,
    float* __restrict__ den) {
  const int bh = blockIdx.x;
  const int s = blockIdx.y;
  const int b = bh >> 4;
  const int h = bh & 15;
  const int n0 = s * 128;

  __shared__ float ek[128][64];
  __shared__ float vf[128][64];

  const int t = threadIdx.x;
  const int rr = t >> 1;
  const int c0 = (t & 1) * 32;
  const size_t base = (size_t)(b * TT + n0 + rr) * 3072 + 1024 + h * 64 + c0;
#pragma unroll
  for (int i = 0; i < 4; ++i) {
    int4 kq = *(const int4*)(qkv + base + i * 8);
    int4 vq = *(const int4*)(qkv + base + 1024 + i * 8);
    const __hip_bfloat16* kp = (const __hip_bfloat16*)&kq;
    const __hip_bfloat16* vp = (const __hip_bfloat16*)&vq;
#pragma unroll
    for (int j = 0; j < 8; ++j) {
      ek[rr][c0 + i * 8 + j] = __expf(__bfloat162float(kp[j]));
      vf[rr][c0 + i * 8 + j] = __bfloat162float(vp[j]);
    }
  }
  __syncthreads();

  const int lane = t & 63, w = t >> 6;
  const int dblk = (lane & 7) | ((w & 1) << 3);
  const int eblk = (lane >> 3) | ((w >> 1) << 3);
  const int d0 = dblk * 4, e0 = eblk * 4;

  float acc[4][4];
#pragma unroll
  for (int i = 0; i < 4; ++i)
#pragma unroll
    for (int j = 0; j < 4; ++j) acc[i][j] = 0.f;

  for (int n = 0; n < 128; ++n) {
    float4 ekv = *(const float4*)&ek[n][d0];
    float4 vv = *(const float4*)&vf[n][e0];
    acc[0][0] += ekv.x * vv.x; acc[0][1] += ekv.x * vv.y;
    acc[0][2] += ekv.x * vv.z; acc[0][3] += ekv.x * vv.w;
    acc[1][0] += ekv.y * vv.x; acc[1][1] += ekv.y * vv.y;
    acc[1][2] += ekv.y * vv.z; acc[1][3] += ekv.y * vv.w;
    acc[2][0] += ekv.z * vv.x; acc[2][1] += ekv.z * vv.y;
    acc[2][2] += ekv.z * vv.z; acc[2][3] += ekv.z * vv.w;
    acc[3][0] += ekv.w * vv.x; acc[3][1] += ekv.w * vv.y;
    acc[3][2] += ekv.w * vv.z; acc[3][3] += ekv.w * vv.w;
  }

  float* pb = part + ((size_t)bh * 32 + s) * 4096;
#pragma unroll
  for (int di = 0; di < 4; ++di) {
    float4 o = {acc[di][0], acc[di][1], acc[di][2], acc[di][3]};
    *(float4*)&pb[(d0 + di) * 64 + e0] = o;
  }

  if (t < 64) {
    float sden = 0.0f;
    for (int n = 0; n < 128; ++n) sden += ek[n][t];
    den[((size_t)bh * 32 + s) * 64 + t] = sden;
  }
}

// ---------------------------------------------------------------------------
// ctxb[bh][d][e] = bf16( (sum_s part) / (sum_s den[d]) ); grid (64,4) x 256
// ---------------------------------------------------------------------------
__global__ __launch_bounds__(256) void ctx_reduce_k(
    const float* __restrict__ part, const float* __restrict__ den,
    __hip_bfloat16* __restrict__ ctxb) {
  const int bh = blockIdx.x, q = blockIdx.y, t = threadIdx.x;
  const int idx = q * 1024 + t * 4;
  const int d = idx >> 6;
  float sden = 0.f;
  for (int s = 0; s < 32; ++s) sden += den[((size_t)bh * 32 + s) * 64 + d];
  float4 sv = {0.f, 0.f, 0.f, 0.f};
  const float* pb = part + (size_t)bh * 32 * 4096 + idx;
  for (int s = 0; s < 32; ++s) {
    float4 v = *(const float4*)(pb + (size_t)s * 4096);
    sv.x += v.x; sv.y += v.y; sv.z += v.z; sv.w += v.w;
  }
  const float di = 1.0f / sden;
  __hip_bfloat16 ob[4] __attribute__((aligned(8)));
  ob[0] = __float2bfloat16(sv.x * di);
  ob[1] = __float2bfloat16(sv.y * di);
  ob[2] = __float2bfloat16(sv.z * di);
  ob[3] = __float2bfloat16(sv.w * di);
  *(int2*)&ctxb[(size_t)bh * 4096 + idx] = *(const int2*)ob;
}

// ---------------------------------------------------------------------------
// q softmax in place: qs = softmax_d(q) * 0.125, bf16. Each 8-lane group
// owns one (row, head); bf16x8 vector I/O; 3-level shfl_xor reduce.
// grid 2048 x 256
// ---------------------------------------------------------------------------
__global__ __launch_bounds__(256) void qsm_k(__hip_bfloat16* __restrict__ qkv) {
  const int t = threadIdx.x;
  const int w = t >> 6, l = t & 63;
  const int n0 = blockIdx.x * 8;
#pragma unroll
  for (int i = 0; i < 4; ++i) {
    const int u = i * 4 + w;          // 0..15
    const int row = n0 + (u >> 1);
    const int half = u & 1;           // heads [half*8, half*8+8)
    __hip_bfloat16* p = qkv + (size_t)row * 3072 + half * 512 + l * 8;
    int4 raw = *(const int4*)p;
    const __hip_bfloat16* bp = (const __hip_bfloat16*)&raw;
    float v[8];
    float m = -1e30f;
#pragma unroll
    for (int j = 0; j < 8; ++j) {
      v[j] = __bfloat162float(bp[j]);
      m = fmaxf(m, v[j]);
    }
    m = fmaxf(m, __shfl_xor(m, 1));
    m = fmaxf(m, __shfl_xor(m, 2));
    m = fmaxf(m, __shfl_xor(m, 4));
    float s = 0.f;
#pragma unroll
    for (int j = 0; j < 8; ++j) {
      v[j] = __expf(v[j] - m);
      s += v[j];
    }
    s += __shfl_xor(s, 1);
    s += __shfl_xor(s, 2);
    s += __shfl_xor(s, 4);
    const float inv = 0.125f / s;
    __hip_bfloat16 o[8] __attribute__((aligned(16)));
#pragma unroll
    for (int j = 0; j < 8; ++j) o[j] = __float2bfloat16(v[j] * inv);
    *(int4*)p = *(const int4*)o;
  }
}

// ---------------------------------------------------------------------------
// WfT[b][n][k] = sum_e ctx[b][h(k)][k&63][e] * Wo[h*64+e][n]  (bf16, MFMA)
// grid (64 bh, 16 n-chunks) x 256 (4 waves x 16 rows)
// ---------------------------------------------------------------------------
__global__ __launch_bounds__(256) void wfuse_k(
    const __hip_bfloat16* __restrict__ WT,
    const __hip_bfloat16* __restrict__ ctxb, __hip_bfloat16* __restrict__ WfT) {
  const int bh = blockIdx.x;
  const int b = bh >> 4, h = bh & 15;
  const int t = threadIdx.x, w = t >> 6, l = t & 63;
  const int n1 = blockIdx.y * 64 + w * 16;
  const int lr = l & 15, hk = l >> 4;

  f32x4 acc[4];
#pragma unroll
  for (int n = 0; n < 4; ++n) acc[n] = (f32x4){0.f, 0.f, 0.f, 0.f};

  const __hip_bfloat16* Abase =
      WT + (size_t)(3072 + n1 + lr) * 1024 + h * 64 + hk * 8;
  const __hip_bfloat16* Bbase = ctxb + (size_t)bh * 4096 + hk * 8;

#pragma unroll
  for (int kk2 = 0; kk2 < 2; ++kk2) {
    bf16x8 af = *(const bf16x8*)(Abase + kk2 * 32);
#pragma unroll
    for (int n = 0; n < 4; ++n) {
      bf16x8 bf = *(const bf16x8*)(Bbase + (n * 16 + lr) * 64 + kk2 * 32);
      acc[n] = __builtin_amdgcn_mfma_f32_16x16x32_bf16(af, bf, acc[n], 0, 0, 0);
    }
  }

  __hip_bfloat16* W0 = WfT + ((size_t)b << 20) + (size_t)(n1 + hk * 4) * 1024 +
                       h * 64 + lr;
#pragma unroll
  for (int n = 0; n < 4; ++n)
#pragma unroll
    for (int j = 0; j < 4; ++j)
      W0[(size_t)j * 1024 + n * 16] = __float2bfloat16(acc[n][j]);
}

// ---------------------------------------------------------------------------
extern "C" void kernel_launch(void* const* d_in, const int* in_sizes, int n_in,
                              void* d_out, int out_size, void* d_ws,
                              size_t ws_size, hipStream_t stream) {
  const float* x = (const float*)d_in[0];
  const float* Wq = (const float*)d_in[1];
  const float* Wk = (const float*)d_in[2];
  const float* Wv = (const float*)d_in[3];
  const float* Wo = (const float*)d_in[4];
  const float* bo = (const float*)d_in[5];
  float* out = (float*)d_out;

  // ws: qkv bf16 [16384][3072] (96MB) | WT bf16 [4096][1024] (8MB)
  //     | den f32 (512KB) | ctxb bf16 (512KB) | WfT bf16 4x[1024][1024] (8MB)
  char* ws = (char*)d_ws;
  __hip_bfloat16* qkv = (__hip_bfloat16*)ws;
  __hip_bfloat16* WT = (__hip_bfloat16*)(ws + 100663296ull);
  float* den = (float*)(ws + 100663296ull + 8388608ull);
  __hip_bfloat16* ctxb =
      (__hip_bfloat16*)(ws + 100663296ull + 8388608ull + 524288ull);
  __hip_bfloat16* WfT =
      (__hip_bfloat16*)(ws + 100663296ull + 8388608ull + 1048576ull);
  // d_out doubles as scratch, fully overwritten by the final GEMM:
  //   [0,32MB) xb bf16; [32,64MB) part f32 [64][32][4096]
  __hip_bfloat16* xb = (__hip_bfloat16*)d_out;
  float* part = (float*)((char*)d_out + 33554432ull);

  const dim3 blk(256);

  xconv_k<<<dim3(NROWS * 1024 / 8 / 256), blk, 0, stream>>>(x, xb);
  wconv_k<<<dim3(16, 16, 4), blk, 0, stream>>>(Wq, Wk, Wv, Wo, WT);

  // QKV projection: [16384,3072] = xb @ [Wq|Wk|Wv]
  mgemm2_k<0, 0><<<dim3(768), dim3(512), 0, stream>>>(xb, 1024, WT, nullptr,
                                                      qkv, 3072, 12);

  ctx_partial_k<<<dim3(64, 32), blk, 0, stream>>>(qkv, part, den);
  ctx_reduce_k<<<dim3(64, 4), blk, 0, stream>>>(part, den, ctxb);
  qsm_k<<<dim3(2048), blk, 0, stream>>>(qkv);
  wfuse_k<<<dim3(64, 16), blk, 0, stream>>>(WT, ctxb, WfT);

  // out = qs @ Wfused[b] + bo
  mgemm2_k<1, 1><<<dim3(256), dim3(512), 0, stream>>>(qkv, 3072, WfT, bo, out,
                                                      1024, 4);
}

// Round 6
// 233.655 us; speedup vs baseline: 1.0379x; 1.0379x over previous
//
#include <hip/hip_runtime.h>
#include <hip/hip_bf16.h>
#include <cstdint>
#include <cstddef>

#define BB 4
#define TT 4096
#define HH 16
#define NROWS 16384  // B*T

typedef __attribute__((ext_vector_type(8))) short bf16x8;
typedef __attribute__((ext_vector_type(4))) float f32x4;

__device__ __forceinline__ void gload_lds16(const void* g, void* l) {
  __builtin_amdgcn_global_load_lds(
      (const __attribute__((address_space(1))) void*)g,
      (__attribute__((address_space(3))) void*)l, 16, 0, 0);
}

template <int N>
__device__ __forceinline__ void wait_vmcnt() {
  if constexpr (N == 8)
    asm volatile("s_waitcnt vmcnt(8)" ::: "memory");
  else if constexpr (N == 4)
    asm volatile("s_waitcnt vmcnt(4)" ::: "memory");
  else
    asm volatile("s_waitcnt vmcnt(0)" ::: "memory");
  __builtin_amdgcn_sched_barrier(0);
}

__device__ __forceinline__ void hbar() {
  asm volatile("s_barrier" ::: "memory");
  __builtin_amdgcn_sched_barrier(0);
}

// ---------------------------------------------------------------------------
// x (f32) -> bf16, 8 elems/thread
// ---------------------------------------------------------------------------
__global__ __launch_bounds__(256) void xconv_k(const float* __restrict__ x,
                                               __hip_bfloat16* __restrict__ xb) {
  const size_t i = ((size_t)blockIdx.x * 256 + threadIdx.x) * 8;
  float4 a = *(const float4*)&x[i];
  float4 b = *(const float4*)&x[i + 4];
  __hip_bfloat16 o[8] __attribute__((aligned(16)));
  o[0] = __float2bfloat16(a.x); o[1] = __float2bfloat16(a.y);
  o[2] = __float2bfloat16(a.z); o[3] = __float2bfloat16(a.w);
  o[4] = __float2bfloat16(b.x); o[5] = __float2bfloat16(b.y);
  o[6] = __float2bfloat16(b.z); o[7] = __float2bfloat16(b.w);
  *(int4*)&xb[i] = *(const int4*)o;
}

// ---------------------------------------------------------------------------
// W [1024][1024] f32 -> WT bf16 transposed; 4 matrices packed.
// ---------------------------------------------------------------------------
__global__ __launch_bounds__(256) void wconv_k(const float* __restrict__ Wq,
                                               const float* __restrict__ Wk,
                                               const float* __restrict__ Wv,
                                               const float* __restrict__ Wo,
                                               __hip_bfloat16* __restrict__ WT) {
  const int which = blockIdx.z;
  const float* W = which == 0 ? Wq : which == 1 ? Wk : which == 2 ? Wv : Wo;
  __shared__ float tile[64][65];
  const int n0 = blockIdx.x * 64, k0 = blockIdx.y * 64;
  const int t = threadIdx.x;
  const int r = t >> 2;
  const int cq = (t & 3) * 16;
#pragma unroll
  for (int i = 0; i < 4; ++i) {
    float4 v = *(const float4*)&W[(size_t)(k0 + r) * 1024 + n0 + cq + i * 4];
    tile[r][cq + i * 4 + 0] = v.x;
    tile[r][cq + i * 4 + 1] = v.y;
    tile[r][cq + i * 4 + 2] = v.z;
    tile[r][cq + i * 4 + 3] = v.w;
  }
  __syncthreads();
  __hip_bfloat16 ob[16] __attribute__((aligned(16)));
#pragma unroll
  for (int j = 0; j < 16; ++j) ob[j] = __float2bfloat16(tile[cq + j][r]);
  __hip_bfloat16* dst = WT + (size_t)(which * 1024 + n0 + r) * 1024 + k0 + cq;
  *(int4*)dst = *(const int4*)&ob[0];
  *(int4*)(dst + 8) = *(const int4*)&ob[8];
}

// ---------------------------------------------------------------------------
// MFMA bf16 GEMM, 256x256 tile, BK=32, ring-4 LDS, counted vmcnt.
// 512 threads = 8 waves (2M x 4N); per-wave output 128x64.
//
// LDS content permutation (dual-constraint, round-6):
//   granule g = 4a+b (16B) of each 16-row block holds
//   (row a, k-octet (b - (a>>1)) & 3).
//  - staging lane map: srow = l>>2, soct = ((l&3) - ((l>>3)&3)) & 3
//    -> each 4-lane group covers one contiguous 64B row segment
//       (round-4 L1/coalescing behavior).
//  - fragment read: lane l reads (row l&15, oct l>>4) at elem
//    lr*32 + ((hk + (lr>>1))&3)*8 -> per-8-lane bank starts
//    {0,16,4,20,8,24,12,28}: all 32 banks, zero conflicts.
// PB: B pointer advances by 1M elems per 4096-row batch (fused Wo path).
// ---------------------------------------------------------------------------
template <int OMODE, int PB>
__global__ __launch_bounds__(512) void mgemm2_k(
    const __hip_bfloat16* __restrict__ A, int lda,
    const __hip_bfloat16* __restrict__ BT, const float* __restrict__ bias,
    void* __restrict__ Cp, int ldc, int gx) {
  __shared__ __hip_bfloat16 lds[4][16384];

  const int t = threadIdx.x;
  const int wid = t >> 6, l = t & 63;
  const int wr = wid >> 2, wc = wid & 3;

  const int nwg = gridDim.x;
  const int cpx = nwg >> 3;
  const int bid = blockIdx.x;
  const int swz = (bid & 7) * cpx + (bid >> 3);
  const int bx = swz % gx, by = swz / gx;
  const int row0 = by * 256, col0 = bx * 256;

  const __hip_bfloat16* BTb = PB ? BT + ((size_t)(row0 >> 12) << 20) : BT;

  // staging lane map: coalesced (4 lanes = 64B row segment), octet rotated
  const int srow = l >> 2;
  const int skel = (((l & 3) - ((l >> 3) & 3)) & 3) * 8;
  const __hip_bfloat16* Ab = A + (size_t)(row0 + wid * 16 + srow) * lda + skel;
  const __hip_bfloat16* Bb =
      BTb + (size_t)(col0 + wid * 16 + srow) * 1024 + skel;

  f32x4 acc[8][4];
#pragma unroll
  for (int m = 0; m < 8; ++m)
#pragma unroll
    for (int n = 0; n < 4; ++n) acc[m][n] = (f32x4){0.f, 0.f, 0.f, 0.f};

  const int lr = l & 15, hk = l >> 4;
  // conflict-free fragment offsets (elems): rotated octet within row
  const int roct = (hk + (lr >> 1)) & 3;
  const int aoff = wr * 4096 + lr * 32 + roct * 8;         // + m*512
  const int boff = 8192 + wc * 2048 + lr * 32 + roct * 8;  // + n*512

  auto stage = [&](int kt, int slot) {
    const int kk = kt * 32;
    __hip_bfloat16* s = &lds[slot][0];
    gload_lds16(Ab + kk, s + wid * 512);
    gload_lds16(Ab + (size_t)128 * lda + kk, s + 4096 + wid * 512);
    gload_lds16(Bb + kk, s + 8192 + wid * 512);
    gload_lds16(Bb + (size_t)128 * 1024 + kk, s + 12288 + wid * 512);
  };

  auto compute = [&](int slot) {
    const __hip_bfloat16* s = &lds[slot][0];
    bf16x8 bf[4];
#pragma unroll
    for (int n = 0; n < 4; ++n) bf[n] = *(const bf16x8*)(s + boff + n * 512);
    __builtin_amdgcn_s_setprio(1);
#pragma unroll
    for (int m = 0; m < 8; ++m) {
      bf16x8 af = *(const bf16x8*)(s + aoff + m * 512);
#pragma unroll
      for (int n = 0; n < 4; ++n)
        acc[m][n] = __builtin_amdgcn_mfma_f32_16x16x32_bf16(af, bf[n],
                                                            acc[m][n], 0, 0, 0);
    }
    __builtin_amdgcn_s_setprio(0);
  };

  stage(0, 0);
  stage(1, 1);
  stage(2, 2);
  for (int kt = 0; kt < 29; ++kt) {
    wait_vmcnt<8>();
    hbar();
    stage(kt + 3, (kt + 3) & 3);
    compute(kt & 3);
  }
  wait_vmcnt<8>(); hbar(); compute(1);
  wait_vmcnt<4>(); hbar(); compute(2);
  wait_vmcnt<0>(); hbar(); compute(3);

  const int cr = hk * 4;
  const int cc = lr;
  if constexpr (OMODE == 0) {
    __hip_bfloat16* C = (__hip_bfloat16*)Cp;
#pragma unroll
    for (int m = 0; m < 8; ++m)
#pragma unroll
      for (int n = 0; n < 4; ++n) {
        const size_t cb = (size_t)(row0 + wr * 128 + m * 16 + cr) * ldc +
                          col0 + wc * 64 + n * 16 + cc;
#pragma unroll
        for (int j = 0; j < 4; ++j)
          C[cb + (size_t)j * ldc] = __float2bfloat16(acc[m][n][j]);
      }
  } else {
    float* C = (float*)Cp;
    float bv[4];
#pragma unroll
    for (int n = 0; n < 4; ++n) bv[n] = bias[col0 + wc * 64 + n * 16 + cc];
#pragma unroll
    for (int m = 0; m < 8; ++m)
#pragma unroll
      for (int n = 0; n < 4; ++n) {
        const size_t cb = (size_t)(row0 + wr * 128 + m * 16 + cr) * ldc +
                          col0 + wc * 64 + n * 16 + cc;
#pragma unroll
        for (int j = 0; j < 4; ++j)
          C[cb + (size_t)j * ldc] = acc[m][n][j] + bv[n];
      }
  }
}

// ---------------------------------------------------------------------------
// context partials; 4d x 4e register microtile, bank-even lane mapping.
// grid (64,32) x 256
// ---------------------------------------------------------------------------
__global__ __launch_bounds__(256) void ctx_partial_k(
    const __hip_bfloat16* __restrict__ qkv, float* __restrict__ part,
    float* __restrict__ den) {
  const int bh = blockIdx.x;
  const int s = blockIdx.y;
  const int b = bh >> 4;
  const int h = bh & 15;
  const int n0 = s * 128;

  __shared__ float ek[128][64];
  __shared__ float vf[128][64];

  const int t = threadIdx.x;
  const int rr = t >> 1;
  const int c0 = (t & 1) * 32;
  const size_t base = (size_t)(b * TT + n0 + rr) * 3072 + 1024 + h * 64 + c0;
#pragma unroll
  for (int i = 0; i < 4; ++i) {
    int4 kq = *(const int4*)(qkv + base + i * 8);
    int4 vq = *(const int4*)(qkv + base + 1024 + i * 8);
    const __hip_bfloat16* kp = (const __hip_bfloat16*)&kq;
    const __hip_bfloat16* vp = (const __hip_bfloat16*)&vq;
#pragma unroll
    for (int j = 0; j < 8; ++j) {
      ek[rr][c0 + i * 8 + j] = __expf(__bfloat162float(kp[j]));
      vf[rr][c0 + i * 8 + j] = __bfloat162float(vp[j]);
    }
  }
  __syncthreads();

  const int lane = t & 63, w = t >> 6;
  const int dblk = (lane & 7) | ((w & 1) << 3);
  const int eblk = (lane >> 3) | ((w >> 1) << 3);
  const int d0 = dblk * 4, e0 = eblk * 4;

  float acc[4][4];
#pragma unroll
  for (int i = 0; i < 4; ++i)
#pragma unroll
    for (int j = 0; j < 4; ++j) acc[i][j] = 0.f;

  for (int n = 0; n < 128; ++n) {
    float4 ekv = *(const float4*)&ek[n][d0];
    float4 vv = *(const float4*)&vf[n][e0];
    acc[0][0] += ekv.x * vv.x; acc[0][1] += ekv.x * vv.y;
    acc[0][2] += ekv.x * vv.z; acc[0][3] += ekv.x * vv.w;
    acc[1][0] += ekv.y * vv.x; acc[1][1] += ekv.y * vv.y;
    acc[1][2] += ekv.y * vv.z; acc[1][3] += ekv.y * vv.w;
    acc[2][0] += ekv.z * vv.x; acc[2][1] += ekv.z * vv.y;
    acc[2][2] += ekv.z * vv.z; acc[2][3] += ekv.z * vv.w;
    acc[3][0] += ekv.w * vv.x; acc[3][1] += ekv.w * vv.y;
    acc[3][2] += ekv.w * vv.z; acc[3][3] += ekv.w * vv.w;
  }

  float* pb = part + ((size_t)bh * 32 + s) * 4096;
#pragma unroll
  for (int di = 0; di < 4; ++di) {
    float4 o = {acc[di][0], acc[di][1], acc[di][2], acc[di][3]};
    *(float4*)&pb[(d0 + di) * 64 + e0] = o;
  }

  if (t < 64) {
    float sden = 0.0f;
    for (int n = 0; n < 128; ++n) sden += ek[n][t];
    den[((size_t)bh * 32 + s) * 64 + t] = sden;
  }
}

// ---------------------------------------------------------------------------
// ctxb[bh][d][e] = bf16( (sum_s part) / (sum_s den[d]) ); grid (64,4) x 256
// ---------------------------------------------------------------------------
__global__ __launch_bounds__(256) void ctx_reduce_k(
    const float* __restrict__ part, const float* __restrict__ den,
    __hip_bfloat16* __restrict__ ctxb) {
  const int bh = blockIdx.x, q = blockIdx.y, t = threadIdx.x;
  const int idx = q * 1024 + t * 4;
  const int d = idx >> 6;
  float sden = 0.f;
  for (int s = 0; s < 32; ++s) sden += den[((size_t)bh * 32 + s) * 64 + d];
  float4 sv = {0.f, 0.f, 0.f, 0.f};
  const float* pb = part + (size_t)bh * 32 * 4096 + idx;
  for (int s = 0; s < 32; ++s) {
    float4 v = *(const float4*)(pb + (size_t)s * 4096);
    sv.x += v.x; sv.y += v.y; sv.z += v.z; sv.w += v.w;
  }
  const float di = 1.0f / sden;
  __hip_bfloat16 ob[4] __attribute__((aligned(8)));
  ob[0] = __float2bfloat16(sv.x * di);
  ob[1] = __float2bfloat16(sv.y * di);
  ob[2] = __float2bfloat16(sv.z * di);
  ob[3] = __float2bfloat16(sv.w * di);
  *(int2*)&ctxb[(size_t)bh * 4096 + idx] = *(const int2*)ob;
}

// ---------------------------------------------------------------------------
// q softmax in place: qs = softmax_d(q) * 0.125, bf16. Each 8-lane group
// owns one (row, head); bf16x8 vector I/O; 3-level shfl_xor reduce.
// grid 2048 x 256
// ---------------------------------------------------------------------------
__global__ __launch_bounds__(256) void qsm_k(__hip_bfloat16* __restrict__ qkv) {
  const int t = threadIdx.x;
  const int w = t >> 6, l = t & 63;
  const int n0 = blockIdx.x * 8;
#pragma unroll
  for (int i = 0; i < 4; ++i) {
    const int u = i * 4 + w;          // 0..15
    const int row = n0 + (u >> 1);
    const int half = u & 1;           // heads [half*8, half*8+8)
    __hip_bfloat16* p = qkv + (size_t)row * 3072 + half * 512 + l * 8;
    int4 raw = *(const int4*)p;
    const __hip_bfloat16* bp = (const __hip_bfloat16*)&raw;
    float v[8];
    float m = -1e30f;
#pragma unroll
    for (int j = 0; j < 8; ++j) {
      v[j] = __bfloat162float(bp[j]);
      m = fmaxf(m, v[j]);
    }
    m = fmaxf(m, __shfl_xor(m, 1));
    m = fmaxf(m, __shfl_xor(m, 2));
    m = fmaxf(m, __shfl_xor(m, 4));
    float s = 0.f;
#pragma unroll
    for (int j = 0; j < 8; ++j) {
      v[j] = __expf(v[j] - m);
      s += v[j];
    }
    s += __shfl_xor(s, 1);
    s += __shfl_xor(s, 2);
    s += __shfl_xor(s, 4);
    const float inv = 0.125f / s;
    __hip_bfloat16 o[8] __attribute__((aligned(16)));
#pragma unroll
    for (int j = 0; j < 8; ++j) o[j] = __float2bfloat16(v[j] * inv);
    *(int4*)p = *(const int4*)o;
  }
}

// ---------------------------------------------------------------------------
// WfT[b][n][k] = sum_e ctx[b][h(k)][k&63][e] * Wo[h*64+e][n]  (bf16, MFMA)
// grid (64 bh, 16 n-chunks) x 256 (4 waves x 16 rows)
// ---------------------------------------------------------------------------
__global__ __launch_bounds__(256) void wfuse_k(
    const __hip_bfloat16* __restrict__ WT,
    const __hip_bfloat16* __restrict__ ctxb, __hip_bfloat16* __restrict__ WfT) {
  const int bh = blockIdx.x;
  const int b = bh >> 4, h = bh & 15;
  const int t = threadIdx.x, w = t >> 6, l = t & 63;
  const int n1 = blockIdx.y * 64 + w * 16;
  const int lr = l & 15, hk = l >> 4;

  f32x4 acc[4];
#pragma unroll
  for (int n = 0; n < 4; ++n) acc[n] = (f32x4){0.f, 0.f, 0.f, 0.f};

  const __hip_bfloat16* Abase =
      WT + (size_t)(3072 + n1 + lr) * 1024 + h * 64 + hk * 8;
  const __hip_bfloat16* Bbase = ctxb + (size_t)bh * 4096 + hk * 8;

#pragma unroll
  for (int kk2 = 0; kk2 < 2; ++kk2) {
    bf16x8 af = *(const bf16x8*)(Abase + kk2 * 32);
#pragma unroll
    for (int n = 0; n < 4; ++n) {
      bf16x8 bf = *(const bf16x8*)(Bbase + (n * 16 + lr) * 64 + kk2 * 32);
      acc[n] = __builtin_amdgcn_mfma_f32_16x16x32_bf16(af, bf, acc[n], 0, 0, 0);
    }
  }

  __hip_bfloat16* W0 = WfT + ((size_t)b << 20) + (size_t)(n1 + hk * 4) * 1024 +
                       h * 64 + lr;
#pragma unroll
  for (int n = 0; n < 4; ++n)
#pragma unroll
    for (int j = 0; j < 4; ++j)
      W0[(size_t)j * 1024 + n * 16] = __float2bfloat16(acc[n][j]);
}

// ---------------------------------------------------------------------------
extern "C" void kernel_launch(void* const* d_in, const int* in_sizes, int n_in,
                              void* d_out, int out_size, void* d_ws,
                              size_t ws_size, hipStream_t stream) {
  const float* x = (const float*)d_in[0];
  const float* Wq = (const float*)d_in[1];
  const float* Wk = (const float*)d_in[2];
  const float* Wv = (const float*)d_in[3];
  const float* Wo = (const float*)d_in[4];
  const float* bo = (const float*)d_in[5];
  float* out = (float*)d_out;

  // ws: qkv bf16 [16384][3072] (96MB) | WT bf16 [4096][1024] (8MB)
  //     | den f32 (512KB) | ctxb bf16 (512KB) | WfT bf16 4x[1024][1024] (8MB)
  char* ws = (char*)d_ws;
  __hip_bfloat16* qkv = (__hip_bfloat16*)ws;
  __hip_bfloat16* WT = (__hip_bfloat16*)(ws + 100663296ull);
  float* den = (float*)(ws + 100663296ull + 8388608ull);
  __hip_bfloat16* ctxb =
      (__hip_bfloat16*)(ws + 100663296ull + 8388608ull + 524288ull);
  __hip_bfloat16* WfT =
      (__hip_bfloat16*)(ws + 100663296ull + 8388608ull + 1048576ull);
  // d_out doubles as scratch, fully overwritten by the final GEMM:
  //   [0,32MB) xb bf16; [32,64MB) part f32 [64][32][4096]
  __hip_bfloat16* xb = (__hip_bfloat16*)d_out;
  float* part = (float*)((char*)d_out + 33554432ull);

  const dim3 blk(256);

  xconv_k<<<dim3(NROWS * 1024 / 8 / 256), blk, 0, stream>>>(x, xb);
  wconv_k<<<dim3(16, 16, 4), blk, 0, stream>>>(Wq, Wk, Wv, Wo, WT);

  // QKV projection: [16384,3072] = xb @ [Wq|Wk|Wv]
  mgemm2_k<0, 0><<<dim3(768), dim3(512), 0, stream>>>(xb, 1024, WT, nullptr,
                                                      qkv, 3072, 12);

  ctx_partial_k<<<dim3(64, 32), blk, 0, stream>>>(qkv, part, den);
  ctx_reduce_k<<<dim3(64, 4), blk, 0, stream>>>(part, den, ctxb);
  qsm_k<<<dim3(2048), blk, 0, stream>>>(qkv);
  wfuse_k<<<dim3(64, 16), blk, 0, stream>>>(WT, ctxb, WfT);

  // out = qs @ Wfused[b] + bo
  mgemm2_k<1, 1><<<dim3(256), dim3(512), 0, stream>>>(qkv, 3072, WfT, bo, out,
                                                      1024, 4);
}

// Round 7
// 228.256 us; speedup vs baseline: 1.0625x; 1.0237x over previous
//
#include <hip/hip_runtime.h>
#include <hip/hip_bf16.h>
#include <cstdint>
#include <cstddef>

#define BB 4
#define TT 4096
#define HH 16
#define NROWS 16384  // B*T

typedef __attribute__((ext_vector_type(8))) short bf16x8;
typedef __attribute__((ext_vector_type(4))) float f32x4;

__device__ __forceinline__ void gload_lds16(const void* g, void* l) {
  __builtin_amdgcn_global_load_lds(
      (const __attribute__((address_space(1))) void*)g,
      (__attribute__((address_space(3))) void*)l, 16, 0, 0);
}

template <int N>
__device__ __forceinline__ void wait_vmcnt() {
  if constexpr (N == 4)
    asm volatile("s_waitcnt vmcnt(4)" ::: "memory");
  else
    asm volatile("s_waitcnt vmcnt(0)" ::: "memory");
  __builtin_amdgcn_sched_barrier(0);
}

__device__ __forceinline__ void hbar() {
  asm volatile("s_barrier" ::: "memory");
  __builtin_amdgcn_sched_barrier(0);
}

// ---------------------------------------------------------------------------
// x (f32) -> bf16, 8 elems/thread
// ---------------------------------------------------------------------------
__global__ __launch_bounds__(256) void xconv_k(const float* __restrict__ x,
                                               __hip_bfloat16* __restrict__ xb) {
  const size_t i = ((size_t)blockIdx.x * 256 + threadIdx.x) * 8;
  float4 a = *(const float4*)&x[i];
  float4 b = *(const float4*)&x[i + 4];
  __hip_bfloat16 o[8] __attribute__((aligned(16)));
  o[0] = __float2bfloat16(a.x); o[1] = __float2bfloat16(a.y);
  o[2] = __float2bfloat16(a.z); o[3] = __float2bfloat16(a.w);
  o[4] = __float2bfloat16(b.x); o[5] = __float2bfloat16(b.y);
  o[6] = __float2bfloat16(b.z); o[7] = __float2bfloat16(b.w);
  *(int4*)&xb[i] = *(const int4*)o;
}

// ---------------------------------------------------------------------------
// W [1024][1024] f32 -> WT bf16 transposed; 4 matrices packed.
// ---------------------------------------------------------------------------
__global__ __launch_bounds__(256) void wconv_k(const float* __restrict__ Wq,
                                               const float* __restrict__ Wk,
                                               const float* __restrict__ Wv,
                                               const float* __restrict__ Wo,
                                               __hip_bfloat16* __restrict__ WT) {
  const int which = blockIdx.z;
  const float* W = which == 0 ? Wq : which == 1 ? Wk : which == 2 ? Wv : Wo;
  __shared__ float tile[64][65];
  const int n0 = blockIdx.x * 64, k0 = blockIdx.y * 64;
  const int t = threadIdx.x;
  const int r = t >> 2;
  const int cq = (t & 3) * 16;
#pragma unroll
  for (int i = 0; i < 4; ++i) {
    float4 v = *(const float4*)&W[(size_t)(k0 + r) * 1024 + n0 + cq + i * 4];
    tile[r][cq + i * 4 + 0] = v.x;
    tile[r][cq + i * 4 + 1] = v.y;
    tile[r][cq + i * 4 + 2] = v.z;
    tile[r][cq + i * 4 + 3] = v.w;
  }
  __syncthreads();
  __hip_bfloat16 ob[16] __attribute__((aligned(16)));
#pragma unroll
  for (int j = 0; j < 16; ++j) ob[j] = __float2bfloat16(tile[cq + j][r]);
  __hip_bfloat16* dst = WT + (size_t)(which * 1024 + n0 + r) * 1024 + k0 + cq;
  *(int4*)dst = *(const int4*)&ob[0];
  *(int4*)(dst + 8) = *(const int4*)&ob[8];
}

// ---------------------------------------------------------------------------
// MFMA bf16 GEMM, 256x256 tile, BK=64, double-buffered LDS, 4 phases/tile.
// 512 threads = 8 waves (2M x 4N); per-wave output 128x64.
//
// LDS per buf (32768 elems): A-c0 | A-c1 | B-c0 | B-c1, each [256 rows][32 k]
// stored as 128 superrows of 8 granules with octet rotation:
//   granule (s, b) holds row 2s+(oct'>>2), k-octet (oct'&3), oct' = (b+s)&7.
//  - staging: 8 consecutive lanes cover rows {2s,2s+1} fully (2x64B
//    contiguous global segments); LDS dest linear (gload_lds constraint).
//  - frag read lane l (lr=l&15, hk=l>>4): slot = ((lr&1)*4+hk-(lr>>1))&7,
//    uniform 2 lanes per 16B bank-group per 16-lane group -> conflict-free.
//
// Schedule per tile t (buf = t&1; stages -> buf^1, regions freed at the
// previous tile boundary, protected by ph1/ph3 vmcnt+barrier):
//   ph1: vmcnt(4); bar; stage A-c0(t+1); read bf(k0)+af(mh0,k0); 16 MFMA
//   ph2:                stage B-c0(t+1); read af(mh1,k0);        16 MFMA
//   ph3: vmcnt(4); bar; stage A-c1(t+1); read bf(k1)+af(mh0,k1); 16 MFMA
//   ph4:                stage B-c1(t+1); read af(mh1,k1);        16 MFMA
// vmcnt(4) = 2 stages (4 gload_lds ops) allowed outstanding; exact by
// issue-order ledger. Last tile: no stages, ph3 waits vmcnt(0).
// PB: B pointer advances by 1M elems per 4096-row batch (fused Wo path).
// ---------------------------------------------------------------------------
template <int OMODE, int PB>
__global__ __launch_bounds__(512) void mgemm3_k(
    const __hip_bfloat16* __restrict__ A, int lda,
    const __hip_bfloat16* __restrict__ BT, const float* __restrict__ bias,
    void* __restrict__ Cp, int ldc, int gx) {
  __shared__ __hip_bfloat16 lds[2][32768];  // 128 KiB

  const int t = threadIdx.x;
  const int wid = t >> 6, l = t & 63;
  const int wr = wid >> 2, wc = wid & 3;

  const int nwg = gridDim.x;
  const int cpx = nwg >> 3;
  const int bid = blockIdx.x;
  const int swz = (bid & 7) * cpx + (bid >> 3);
  const int bx = swz % gx, by = swz / gx;
  const int row0 = by * 256, col0 = bx * 256;

  const __hip_bfloat16* BTb = PB ? BT + ((size_t)(row0 >> 12) << 20) : BT;

  // staging per-lane source geometry (instr i=0/1 adds 16 rows)
  const int sg = l >> 3;                 // superrow within instr
  const int octp = ((l & 7) + sg) & 7;   // rotated octet
  const int koct = octp & 3;             // k-octet (8 elems)
  const int srow = 2 * (wid * 16 + sg) + (octp >> 2);
  const __hip_bfloat16* As0 = A + (size_t)(row0 + srow) * lda + koct * 8;
  const __hip_bfloat16* Bs0 = BTb + (size_t)(col0 + srow) * 1024 + koct * 8;

  f32x4 acc[8][4];
#pragma unroll
  for (int m = 0; m < 8; ++m)
#pragma unroll
    for (int n = 0; n < 4; ++n) acc[m][n] = (f32x4){0.f, 0.f, 0.f, 0.f};

  const int lr = l & 15, hk = l >> 4;
  // per-lane read offset within a 512-elem (16-row) frag block
  const int slot = (((lr & 1) << 2) + hk - (lr >> 1)) & 7;
  const int rdo = (lr >> 1) * 64 + slot * 8;

  auto stageA = [&](int tn, int c) {
    __hip_bfloat16* d = &lds[tn & 1][c * 8192 + wid * 1024];
    const __hip_bfloat16* s = As0 + tn * 64 + c * 32;
    gload_lds16(s, d);
    gload_lds16(s + (size_t)16 * lda, d + 512);
  };
  auto stageB = [&](int tn, int c) {
    __hip_bfloat16* d = &lds[tn & 1][16384 + c * 8192 + wid * 1024];
    const __hip_bfloat16* s = Bs0 + tn * 64 + c * 32;
    gload_lds16(s, d);
    gload_lds16(s + (size_t)16 * 1024, d + 512);
  };

  // prologue: tile 0 -> buf 0 (8 ops)
  stageA(0, 0); stageB(0, 0); stageA(0, 1); stageB(0, 1);

  const __hip_bfloat16* sb = &lds[0][0];
  for (int tn = 0; tn < 16; ++tn) {
    const int bufo = (tn & 1) * 32768;
    const bool pre = tn < 15;
    bf16x8 bfv[4], afv[4];

    // ===== kstep 0 =====
    wait_vmcnt<4>();
    hbar();
    if (pre) stageA(tn + 1, 0);
#pragma unroll
    for (int n = 0; n < 4; ++n)
      bfv[n] = *(const bf16x8*)(sb + bufo + 16384 + wc * 2048 + n * 512 + rdo);
#pragma unroll
    for (int j = 0; j < 4; ++j)
      afv[j] = *(const bf16x8*)(sb + bufo + wr * 4096 + j * 512 + rdo);
    __builtin_amdgcn_s_setprio(1);
#pragma unroll
    for (int j = 0; j < 4; ++j)
#pragma unroll
      for (int n = 0; n < 4; ++n)
        acc[j][n] = __builtin_amdgcn_mfma_f32_16x16x32_bf16(afv[j], bfv[n],
                                                            acc[j][n], 0, 0, 0);
    __builtin_amdgcn_s_setprio(0);
    if (pre) stageB(tn + 1, 0);
#pragma unroll
    for (int j = 0; j < 4; ++j)
      afv[j] = *(const bf16x8*)(sb + bufo + wr * 4096 + 2048 + j * 512 + rdo);
    __builtin_amdgcn_s_setprio(1);
#pragma unroll
    for (int j = 0; j < 4; ++j)
#pragma unroll
      for (int n = 0; n < 4; ++n)
        acc[4 + j][n] = __builtin_amdgcn_mfma_f32_16x16x32_bf16(
            afv[j], bfv[n], acc[4 + j][n], 0, 0, 0);
    __builtin_amdgcn_s_setprio(0);

    // ===== kstep 1 =====
    if (pre)
      wait_vmcnt<4>();
    else
      wait_vmcnt<0>();
    hbar();
    if (pre) stageA(tn + 1, 1);
#pragma unroll
    for (int n = 0; n < 4; ++n)
      bfv[n] = *(const bf16x8*)(sb + bufo + 8192 + 16384 + wc * 2048 +
                                n * 512 + rdo);
#pragma unroll
    for (int j = 0; j < 4; ++j)
      afv[j] = *(const bf16x8*)(sb + bufo + 8192 + wr * 4096 + j * 512 + rdo);
    __builtin_amdgcn_s_setprio(1);
#pragma unroll
    for (int j = 0; j < 4; ++j)
#pragma unroll
      for (int n = 0; n < 4; ++n)
        acc[j][n] = __builtin_amdgcn_mfma_f32_16x16x32_bf16(afv[j], bfv[n],
                                                            acc[j][n], 0, 0, 0);
    __builtin_amdgcn_s_setprio(0);
    if (pre) stageB(tn + 1, 1);
#pragma unroll
    for (int j = 0; j < 4; ++j)
      afv[j] = *(const bf16x8*)(sb + bufo + 8192 + wr * 4096 + 2048 + j * 512 +
                                rdo);
    __builtin_amdgcn_s_setprio(1);
#pragma unroll
    for (int j = 0; j < 4; ++j)
#pragma unroll
      for (int n = 0; n < 4; ++n)
        acc[4 + j][n] = __builtin_amdgcn_mfma_f32_16x16x32_bf16(
            afv[j], bfv[n], acc[4 + j][n], 0, 0, 0);
    __builtin_amdgcn_s_setprio(0);
  }

  const int cr = hk * 4;
  const int cc = lr;
  if constexpr (OMODE == 0) {
    __hip_bfloat16* C = (__hip_bfloat16*)Cp;
#pragma unroll
    for (int m = 0; m < 8; ++m)
#pragma unroll
      for (int n = 0; n < 4; ++n) {
        const size_t cb = (size_t)(row0 + wr * 128 + m * 16 + cr) * ldc +
                          col0 + wc * 64 + n * 16 + cc;
#pragma unroll
        for (int j = 0; j < 4; ++j)
          C[cb + (size_t)j * ldc] = __float2bfloat16(acc[m][n][j]);
      }
  } else {
    float* C = (float*)Cp;
    float bv[4];
#pragma unroll
    for (int n = 0; n < 4; ++n) bv[n] = bias[col0 + wc * 64 + n * 16 + cc];
#pragma unroll
    for (int m = 0; m < 8; ++m)
#pragma unroll
      for (int n = 0; n < 4; ++n) {
        const size_t cb = (size_t)(row0 + wr * 128 + m * 16 + cr) * ldc +
                          col0 + wc * 64 + n * 16 + cc;
#pragma unroll
        for (int j = 0; j < 4; ++j)
          C[cb + (size_t)j * ldc] = acc[m][n][j] + bv[n];
      }
  }
}

// ---------------------------------------------------------------------------
// context partials; 4d x 4e register microtile, bank-even lane mapping.
// grid (64,32) x 256
// ---------------------------------------------------------------------------
__global__ __launch_bounds__(256) void ctx_partial_k(
    const __hip_bfloat16* __restrict__ qkv, float* __restrict__ part,
    float* __restrict__ den) {
  const int bh = blockIdx.x;
  const int s = blockIdx.y;
  const int b = bh >> 4;
  const int h = bh & 15;
  const int n0 = s * 128;

  __shared__ float ek[128][64];
  __shared__ float vf[128][64];

  const int t = threadIdx.x;
  const int rr = t >> 1;
  const int c0 = (t & 1) * 32;
  const size_t base = (size_t)(b * TT + n0 + rr) * 3072 + 1024 + h * 64 + c0;
#pragma unroll
  for (int i = 0; i < 4; ++i) {
    int4 kq = *(const int4*)(qkv + base + i * 8);
    int4 vq = *(const int4*)(qkv + base + 1024 + i * 8);
    const __hip_bfloat16* kp = (const __hip_bfloat16*)&kq;
    const __hip_bfloat16* vp = (const __hip_bfloat16*)&vq;
#pragma unroll
    for (int j = 0; j < 8; ++j) {
      ek[rr][c0 + i * 8 + j] = __expf(__bfloat162float(kp[j]));
      vf[rr][c0 + i * 8 + j] = __bfloat162float(vp[j]);
    }
  }
  __syncthreads();

  const int lane = t & 63, w = t >> 6;
  const int dblk = (lane & 7) | ((w & 1) << 3);
  const int eblk = (lane >> 3) | ((w >> 1) << 3);
  const int d0 = dblk * 4, e0 = eblk * 4;

  float acc[4][4];
#pragma unroll
  for (int i = 0; i < 4; ++i)
#pragma unroll
    for (int j = 0; j < 4; ++j) acc[i][j] = 0.f;

  for (int n = 0; n < 128; ++n) {
    float4 ekv = *(const float4*)&ek[n][d0];
    float4 vv = *(const float4*)&vf[n][e0];
    acc[0][0] += ekv.x * vv.x; acc[0][1] += ekv.x * vv.y;
    acc[0][2] += ekv.x * vv.z; acc[0][3] += ekv.x * vv.w;
    acc[1][0] += ekv.y * vv.x; acc[1][1] += ekv.y * vv.y;
    acc[1][2] += ekv.y * vv.z; acc[1][3] += ekv.y * vv.w;
    acc[2][0] += ekv.z * vv.x; acc[2][1] += ekv.z * vv.y;
    acc[2][2] += ekv.z * vv.z; acc[2][3] += ekv.z * vv.w;
    acc[3][0] += ekv.w * vv.x; acc[3][1] += ekv.w * vv.y;
    acc[3][2] += ekv.w * vv.z; acc[3][3] += ekv.w * vv.w;
  }

  float* pb = part + ((size_t)bh * 32 + s) * 4096;
#pragma unroll
  for (int di = 0; di < 4; ++di) {
    float4 o = {acc[di][0], acc[di][1], acc[di][2], acc[di][3]};
    *(float4*)&pb[(d0 + di) * 64 + e0] = o;
  }

  if (t < 64) {
    float sden = 0.0f;
    for (int n = 0; n < 128; ++n) sden += ek[n][t];
    den[((size_t)bh * 32 + s) * 64 + t] = sden;
  }
}

// ---------------------------------------------------------------------------
// ctxb[bh][d][e] = bf16( (sum_s part) / (sum_s den[d]) ); grid (64,4) x 256
// ---------------------------------------------------------------------------
__global__ __launch_bounds__(256) void ctx_reduce_k(
    const float* __restrict__ part, const float* __restrict__ den,
    __hip_bfloat16* __restrict__ ctxb) {
  const int bh = blockIdx.x, q = blockIdx.y, t = threadIdx.x;
  const int idx = q * 1024 + t * 4;
  const int d = idx >> 6;
  float sden = 0.f;
  for (int s = 0; s < 32; ++s) sden += den[((size_t)bh * 32 + s) * 64 + d];
  float4 sv = {0.f, 0.f, 0.f, 0.f};
  const float* pb = part + (size_t)bh * 32 * 4096 + idx;
  for (int s = 0; s < 32; ++s) {
    float4 v = *(const float4*)(pb + (size_t)s * 4096);
    sv.x += v.x; sv.y += v.y; sv.z += v.z; sv.w += v.w;
  }
  const float di = 1.0f / sden;
  __hip_bfloat16 ob[4] __attribute__((aligned(8)));
  ob[0] = __float2bfloat16(sv.x * di);
  ob[1] = __float2bfloat16(sv.y * di);
  ob[2] = __float2bfloat16(sv.z * di);
  ob[3] = __float2bfloat16(sv.w * di);
  *(int2*)&ctxb[(size_t)bh * 4096 + idx] = *(const int2*)ob;
}

// ---------------------------------------------------------------------------
// q softmax in place: qs = softmax_d(q) * 0.125, bf16. Each 8-lane group
// owns one (row, head); bf16x8 vector I/O; 3-level shfl_xor reduce.
// grid 2048 x 256
// ---------------------------------------------------------------------------
__global__ __launch_bounds__(256) void qsm_k(__hip_bfloat16* __restrict__ qkv) {
  const int t = threadIdx.x;
  const int w = t >> 6, l = t & 63;
  const int n0 = blockIdx.x * 8;
#pragma unroll
  for (int i = 0; i < 4; ++i) {
    const int u = i * 4 + w;          // 0..15
    const int row = n0 + (u >> 1);
    const int half = u & 1;           // heads [half*8, half*8+8)
    __hip_bfloat16* p = qkv + (size_t)row * 3072 + half * 512 + l * 8;
    int4 raw = *(const int4*)p;
    const __hip_bfloat16* bp = (const __hip_bfloat16*)&raw;
    float v[8];
    float m = -1e30f;
#pragma unroll
    for (int j = 0; j < 8; ++j) {
      v[j] = __bfloat162float(bp[j]);
      m = fmaxf(m, v[j]);
    }
    m = fmaxf(m, __shfl_xor(m, 1));
    m = fmaxf(m, __shfl_xor(m, 2));
    m = fmaxf(m, __shfl_xor(m, 4));
    float s = 0.f;
#pragma unroll
    for (int j = 0; j < 8; ++j) {
      v[j] = __expf(v[j] - m);
      s += v[j];
    }
    s += __shfl_xor(s, 1);
    s += __shfl_xor(s, 2);
    s += __shfl_xor(s, 4);
    const float inv = 0.125f / s;
    __hip_bfloat16 o[8] __attribute__((aligned(16)));
#pragma unroll
    for (int j = 0; j < 8; ++j) o[j] = __float2bfloat16(v[j] * inv);
    *(int4*)p = *(const int4*)o;
  }
}

// ---------------------------------------------------------------------------
// WfT[b][n][k] = sum_e ctx[b][h(k)][k&63][e] * Wo[h*64+e][n]  (bf16, MFMA)
// grid (64 bh, 16 n-chunks) x 256 (4 waves x 16 rows)
// ---------------------------------------------------------------------------
__global__ __launch_bounds__(256) void wfuse_k(
    const __hip_bfloat16* __restrict__ WT,
    const __hip_bfloat16* __restrict__ ctxb, __hip_bfloat16* __restrict__ WfT) {
  const int bh = blockIdx.x;
  const int b = bh >> 4, h = bh & 15;
  const int t = threadIdx.x, w = t >> 6, l = t & 63;
  const int n1 = blockIdx.y * 64 + w * 16;
  const int lr = l & 15, hk = l >> 4;

  f32x4 acc[4];
#pragma unroll
  for (int n = 0; n < 4; ++n) acc[n] = (f32x4){0.f, 0.f, 0.f, 0.f};

  const __hip_bfloat16* Abase =
      WT + (size_t)(3072 + n1 + lr) * 1024 + h * 64 + hk * 8;
  const __hip_bfloat16* Bbase = ctxb + (size_t)bh * 4096 + hk * 8;

#pragma unroll
  for (int kk2 = 0; kk2 < 2; ++kk2) {
    bf16x8 af = *(const bf16x8*)(Abase + kk2 * 32);
#pragma unroll
    for (int n = 0; n < 4; ++n) {
      bf16x8 bf = *(const bf16x8*)(Bbase + (n * 16 + lr) * 64 + kk2 * 32);
      acc[n] = __builtin_amdgcn_mfma_f32_16x16x32_bf16(af, bf, acc[n], 0, 0, 0);
    }
  }

  __hip_bfloat16* W0 = WfT + ((size_t)b << 20) + (size_t)(n1 + hk * 4) * 1024 +
                       h * 64 + lr;
#pragma unroll
  for (int n = 0; n < 4; ++n)
#pragma unroll
    for (int j = 0; j < 4; ++j)
      W0[(size_t)j * 1024 + n * 16] = __float2bfloat16(acc[n][j]);
}

// ---------------------------------------------------------------------------
extern "C" void kernel_launch(void* const* d_in, const int* in_sizes, int n_in,
                              void* d_out, int out_size, void* d_ws,
                              size_t ws_size, hipStream_t stream) {
  const float* x = (const float*)d_in[0];
  const float* Wq = (const float*)d_in[1];
  const float* Wk = (const float*)d_in[2];
  const float* Wv = (const float*)d_in[3];
  const float* Wo = (const float*)d_in[4];
  const float* bo = (const float*)d_in[5];
  float* out = (float*)d_out;

  // ws: qkv bf16 [16384][3072] (96MB) | WT bf16 [4096][1024] (8MB)
  //     | den f32 (512KB) | ctxb bf16 (512KB) | WfT bf16 4x[1024][1024] (8MB)
  char* ws = (char*)d_ws;
  __hip_bfloat16* qkv = (__hip_bfloat16*)ws;
  __hip_bfloat16* WT = (__hip_bfloat16*)(ws + 100663296ull);
  float* den = (float*)(ws + 100663296ull + 8388608ull);
  __hip_bfloat16* ctxb =
      (__hip_bfloat16*)(ws + 100663296ull + 8388608ull + 524288ull);
  __hip_bfloat16* WfT =
      (__hip_bfloat16*)(ws + 100663296ull + 8388608ull + 1048576ull);
  // d_out doubles as scratch, fully overwritten by the final GEMM:
  //   [0,32MB) xb bf16; [32,64MB) part f32 [64][32][4096]
  __hip_bfloat16* xb = (__hip_bfloat16*)d_out;
  float* part = (float*)((char*)d_out + 33554432ull);

  const dim3 blk(256);

  xconv_k<<<dim3(NROWS * 1024 / 8 / 256), blk, 0, stream>>>(x, xb);
  wconv_k<<<dim3(16, 16, 4), blk, 0, stream>>>(Wq, Wk, Wv, Wo, WT);

  // QKV projection: [16384,3072] = xb @ [Wq|Wk|Wv]
  mgemm3_k<0, 0><<<dim3(768), dim3(512), 0, stream>>>(xb, 1024, WT, nullptr,
                                                      qkv, 3072, 12);

  ctx_partial_k<<<dim3(64, 32), blk, 0, stream>>>(qkv, part, den);
  ctx_reduce_k<<<dim3(64, 4), blk, 0, stream>>>(part, den, ctxb);
  qsm_k<<<dim3(2048), blk, 0, stream>>>(qkv);
  wfuse_k<<<dim3(64, 16), blk, 0, stream>>>(WT, ctxb, WfT);

  // out = qs @ Wfused[b] + bo
  mgemm3_k<1, 1><<<dim3(256), dim3(512), 0, stream>>>(qkv, 3072, WfT, bo, out,
                                                      1024, 4);
}

// Round 8
// 195.442 us; speedup vs baseline: 1.2408x; 1.1679x over previous
//
#include <hip/hip_runtime.h>
#include <hip/hip_bf16.h>
#include <cstdint>
#include <cstddef>

#define BB 4
#define TT 4096
#define HH 16
#define NROWS 16384  // B*T

typedef __attribute__((ext_vector_type(8))) short bf16x8;
typedef __attribute__((ext_vector_type(4))) float f32x4;

__device__ __forceinline__ void gload_lds16(const void* g, void* l) {
  __builtin_amdgcn_global_load_lds(
      (const __attribute__((address_space(1))) void*)g,
      (__attribute__((address_space(3))) void*)l, 16, 0, 0);
}

template <int N>
__device__ __forceinline__ void wait_vmcnt() {
  if constexpr (N == 4)
    asm volatile("s_waitcnt vmcnt(4)" ::: "memory");
  else
    asm volatile("s_waitcnt vmcnt(0)" ::: "memory");
  __builtin_amdgcn_sched_barrier(0);
}

__device__ __forceinline__ void hbar() {
  asm volatile("s_barrier" ::: "memory");
  __builtin_amdgcn_sched_barrier(0);
}

// ---------------------------------------------------------------------------
// x (f32) -> bf16, 8 elems/thread
// ---------------------------------------------------------------------------
__global__ __launch_bounds__(256) void xconv_k(const float* __restrict__ x,
                                               __hip_bfloat16* __restrict__ xb) {
  const size_t i = ((size_t)blockIdx.x * 256 + threadIdx.x) * 8;
  float4 a = *(const float4*)&x[i];
  float4 b = *(const float4*)&x[i + 4];
  __hip_bfloat16 o[8] __attribute__((aligned(16)));
  o[0] = __float2bfloat16(a.x); o[1] = __float2bfloat16(a.y);
  o[2] = __float2bfloat16(a.z); o[3] = __float2bfloat16(a.w);
  o[4] = __float2bfloat16(b.x); o[5] = __float2bfloat16(b.y);
  o[6] = __float2bfloat16(b.z); o[7] = __float2bfloat16(b.w);
  *(int4*)&xb[i] = *(const int4*)o;
}

// ---------------------------------------------------------------------------
// W [1024][1024] f32 -> WT bf16 transposed; 4 matrices packed.
// ---------------------------------------------------------------------------
__global__ __launch_bounds__(256) void wconv_k(const float* __restrict__ Wq,
                                               const float* __restrict__ Wk,
                                               const float* __restrict__ Wv,
                                               const float* __restrict__ Wo,
                                               __hip_bfloat16* __restrict__ WT) {
  const int which = blockIdx.z;
  const float* W = which == 0 ? Wq : which == 1 ? Wk : which == 2 ? Wv : Wo;
  __shared__ float tile[64][65];
  const int n0 = blockIdx.x * 64, k0 = blockIdx.y * 64;
  const int t = threadIdx.x;
  const int r = t >> 2;
  const int cq = (t & 3) * 16;
#pragma unroll
  for (int i = 0; i < 4; ++i) {
    float4 v = *(const float4*)&W[(size_t)(k0 + r) * 1024 + n0 + cq + i * 4];
    tile[r][cq + i * 4 + 0] = v.x;
    tile[r][cq + i * 4 + 1] = v.y;
    tile[r][cq + i * 4 + 2] = v.z;
    tile[r][cq + i * 4 + 3] = v.w;
  }
  __syncthreads();
  __hip_bfloat16 ob[16] __attribute__((aligned(16)));
#pragma unroll
  for (int j = 0; j < 16; ++j) ob[j] = __float2bfloat16(tile[cq + j][r]);
  __hip_bfloat16* dst = WT + (size_t)(which * 1024 + n0 + r) * 1024 + k0 + cq;
  *(int4*)dst = *(const int4*)&ob[0];
  *(int4*)(dst + 8) = *(const int4*)&ob[8];
}

// ---------------------------------------------------------------------------
// MFMA bf16 GEMM, 256x256 tile, BK=64, double-buffered LDS, 4 phases/tile.
// (unchanged from round 7 — best known: 106 us QKV, MfmaUtil 43.5%)
// ---------------------------------------------------------------------------
template <int OMODE, int PB>
__global__ __launch_bounds__(512) void mgemm3_k(
    const __hip_bfloat16* __restrict__ A, int lda,
    const __hip_bfloat16* __restrict__ BT, const float* __restrict__ bias,
    void* __restrict__ Cp, int ldc, int gx) {
  __shared__ __hip_bfloat16 lds[2][32768];  // 128 KiB

  const int t = threadIdx.x;
  const int wid = t >> 6, l = t & 63;
  const int wr = wid >> 2, wc = wid & 3;

  const int nwg = gridDim.x;
  const int cpx = nwg >> 3;
  const int bid = blockIdx.x;
  const int swz = (bid & 7) * cpx + (bid >> 3);
  const int bx = swz % gx, by = swz / gx;
  const int row0 = by * 256, col0 = bx * 256;

  const __hip_bfloat16* BTb = PB ? BT + ((size_t)(row0 >> 12) << 20) : BT;

  const int sg = l >> 3;
  const int octp = ((l & 7) + sg) & 7;
  const int koct = octp & 3;
  const int srow = 2 * (wid * 16 + sg) + (octp >> 2);
  const __hip_bfloat16* As0 = A + (size_t)(row0 + srow) * lda + koct * 8;
  const __hip_bfloat16* Bs0 = BTb + (size_t)(col0 + srow) * 1024 + koct * 8;

  f32x4 acc[8][4];
#pragma unroll
  for (int m = 0; m < 8; ++m)
#pragma unroll
    for (int n = 0; n < 4; ++n) acc[m][n] = (f32x4){0.f, 0.f, 0.f, 0.f};

  const int lr = l & 15, hk = l >> 4;
  const int slot = (((lr & 1) << 2) + hk - (lr >> 1)) & 7;
  const int rdo = (lr >> 1) * 64 + slot * 8;

  auto stageA = [&](int tn, int c) {
    __hip_bfloat16* d = &lds[tn & 1][c * 8192 + wid * 1024];
    const __hip_bfloat16* s = As0 + tn * 64 + c * 32;
    gload_lds16(s, d);
    gload_lds16(s + (size_t)16 * lda, d + 512);
  };
  auto stageB = [&](int tn, int c) {
    __hip_bfloat16* d = &lds[tn & 1][16384 + c * 8192 + wid * 1024];
    const __hip_bfloat16* s = Bs0 + tn * 64 + c * 32;
    gload_lds16(s, d);
    gload_lds16(s + (size_t)16 * 1024, d + 512);
  };

  stageA(0, 0); stageB(0, 0); stageA(0, 1); stageB(0, 1);

  const __hip_bfloat16* sb = &lds[0][0];
  for (int tn = 0; tn < 16; ++tn) {
    const int bufo = (tn & 1) * 32768;
    const bool pre = tn < 15;
    bf16x8 bfv[4], afv[4];

    // ===== kstep 0 =====
    wait_vmcnt<4>();
    hbar();
    if (pre) stageA(tn + 1, 0);
#pragma unroll
    for (int n = 0; n < 4; ++n)
      bfv[n] = *(const bf16x8*)(sb + bufo + 16384 + wc * 2048 + n * 512 + rdo);
#pragma unroll
    for (int j = 0; j < 4; ++j)
      afv[j] = *(const bf16x8*)(sb + bufo + wr * 4096 + j * 512 + rdo);
    __builtin_amdgcn_s_setprio(1);
#pragma unroll
    for (int j = 0; j < 4; ++j)
#pragma unroll
      for (int n = 0; n < 4; ++n)
        acc[j][n] = __builtin_amdgcn_mfma_f32_16x16x32_bf16(afv[j], bfv[n],
                                                            acc[j][n], 0, 0, 0);
    __builtin_amdgcn_s_setprio(0);
    if (pre) stageB(tn + 1, 0);
#pragma unroll
    for (int j = 0; j < 4; ++j)
      afv[j] = *(const bf16x8*)(sb + bufo + wr * 4096 + 2048 + j * 512 + rdo);
    __builtin_amdgcn_s_setprio(1);
#pragma unroll
    for (int j = 0; j < 4; ++j)
#pragma unroll
      for (int n = 0; n < 4; ++n)
        acc[4 + j][n] = __builtin_amdgcn_mfma_f32_16x16x32_bf16(
            afv[j], bfv[n], acc[4 + j][n], 0, 0, 0);
    __builtin_amdgcn_s_setprio(0);

    // ===== kstep 1 =====
    if (pre)
      wait_vmcnt<4>();
    else
      wait_vmcnt<0>();
    hbar();
    if (pre) stageA(tn + 1, 1);
#pragma unroll
    for (int n = 0; n < 4; ++n)
      bfv[n] = *(const bf16x8*)(sb + bufo + 8192 + 16384 + wc * 2048 +
                                n * 512 + rdo);
#pragma unroll
    for (int j = 0; j < 4; ++j)
      afv[j] = *(const bf16x8*)(sb + bufo + 8192 + wr * 4096 + j * 512 + rdo);
    __builtin_amdgcn_s_setprio(1);
#pragma unroll
    for (int j = 0; j < 4; ++j)
#pragma unroll
      for (int n = 0; n < 4; ++n)
        acc[j][n] = __builtin_amdgcn_mfma_f32_16x16x32_bf16(afv[j], bfv[n],
                                                            acc[j][n], 0, 0, 0);
    __builtin_amdgcn_s_setprio(0);
    if (pre) stageB(tn + 1, 1);
#pragma unroll
    for (int j = 0; j < 4; ++j)
      afv[j] = *(const bf16x8*)(sb + bufo + 8192 + wr * 4096 + 2048 + j * 512 +
                                rdo);
    __builtin_amdgcn_s_setprio(1);
#pragma unroll
    for (int j = 0; j < 4; ++j)
#pragma unroll
      for (int n = 0; n < 4; ++n)
        acc[4 + j][n] = __builtin_amdgcn_mfma_f32_16x16x32_bf16(
            afv[j], bfv[n], acc[4 + j][n], 0, 0, 0);
    __builtin_amdgcn_s_setprio(0);
  }

  const int cr = hk * 4;
  const int cc = lr;
  if constexpr (OMODE == 0) {
    __hip_bfloat16* C = (__hip_bfloat16*)Cp;
#pragma unroll
    for (int m = 0; m < 8; ++m)
#pragma unroll
      for (int n = 0; n < 4; ++n) {
        const size_t cb = (size_t)(row0 + wr * 128 + m * 16 + cr) * ldc +
                          col0 + wc * 64 + n * 16 + cc;
#pragma unroll
        for (int j = 0; j < 4; ++j)
          C[cb + (size_t)j * ldc] = __float2bfloat16(acc[m][n][j]);
      }
  } else {
    float* C = (float*)Cp;
    float bv[4];
#pragma unroll
    for (int n = 0; n < 4; ++n) bv[n] = bias[col0 + wc * 64 + n * 16 + cc];
#pragma unroll
    for (int m = 0; m < 8; ++m)
#pragma unroll
      for (int n = 0; n < 4; ++n) {
        const size_t cb = (size_t)(row0 + wr * 128 + m * 16 + cr) * ldc +
                          col0 + wc * 64 + n * 16 + cc;
#pragma unroll
        for (int j = 0; j < 4; ++j)
          C[cb + (size_t)j * ldc] = acc[m][n][j] + bv[n];
      }
  }
}

// ---------------------------------------------------------------------------
// Fused: q-softmax (in place) + context partials via MFMA.
// Block (bh, s): 128 rows of (b,h).
//  phase 0: issue k/v loads; q-softmax for same rows/head (hides latency)
//  phase 1: ek=exp(k), v -> TRANSPOSED bf16 LDS: ekT[d][n], vfT[e][n];
//           rows [64][136]+pad, d>=32 region offset +32 elems (banks of the
//           even/odd write runs disjoint; read granule classes uniform).
//  phase 2: part[d][e] = sum_n ekT[d][n]*vfT[e][n] -- 16 MFMA/wave
//           (wave = 16-row d-strip, 4 e-frags, 4 ksteps of K=32).
//  phase 3: den[d] = sum_n ekT[d][n] (threads t%4==0), part/den stores.
// grid (64, 32) x 256
// ---------------------------------------------------------------------------
__global__ __launch_bounds__(256) void ctxq_k(__hip_bfloat16* __restrict__ qkv,
                                              float* __restrict__ part,
                                              float* __restrict__ den) {
  __shared__ __hip_bfloat16 ldsb[2 * 8736];
  __hip_bfloat16* ekT = ldsb;
  __hip_bfloat16* vfT = ldsb + 8736;

  const int bh = blockIdx.x;
  const int s = blockIdx.y;
  const int b = bh >> 4;
  const int h = bh & 15;
  const int n0 = s * 128;
  const int t = threadIdx.x;

  // ---- issue k/v loads ----
  const int rr = t >> 1;
  const int c0 = (t & 1) * 32;
  const size_t base = (size_t)(b * TT + n0 + rr) * 3072 + 1024 + h * 64 + c0;
  int4 kq[4], vq[4];
#pragma unroll
  for (int i = 0; i < 4; ++i) {
    kq[i] = *(const int4*)(qkv + base + i * 8);
    vq[i] = *(const int4*)(qkv + base + 1024 + i * 8);
  }

  // ---- fused q softmax (independent of k/v) ----
  {
    const int g8 = t >> 3;
    const int lc = (t & 7) * 8;
#pragma unroll
    for (int it = 0; it < 4; ++it) {
      const int r = it * 32 + g8;
      __hip_bfloat16* p =
          qkv + (size_t)(b * TT + n0 + r) * 3072 + h * 64 + lc;
      int4 raw = *(const int4*)p;
      const __hip_bfloat16* bp = (const __hip_bfloat16*)&raw;
      float v[8];
      float m = -1e30f;
#pragma unroll
      for (int j = 0; j < 8; ++j) {
        v[j] = __bfloat162float(bp[j]);
        m = fmaxf(m, v[j]);
      }
      m = fmaxf(m, __shfl_xor(m, 1));
      m = fmaxf(m, __shfl_xor(m, 2));
      m = fmaxf(m, __shfl_xor(m, 4));
      float sm = 0.f;
#pragma unroll
      for (int j = 0; j < 8; ++j) {
        v[j] = __expf(v[j] - m);
        sm += v[j];
      }
      sm += __shfl_xor(sm, 1);
      sm += __shfl_xor(sm, 2);
      sm += __shfl_xor(sm, 4);
      const float inv = 0.125f / sm;
      __hip_bfloat16 o[8] __attribute__((aligned(16)));
#pragma unroll
      for (int j = 0; j < 8; ++j) o[j] = __float2bfloat16(v[j] * inv);
      *(int4*)p = *(const int4*)o;
    }
  }

  // ---- exp(k), v -> transposed LDS ----
#pragma unroll
  for (int i = 0; i < 4; ++i) {
    const __hip_bfloat16* kp = (const __hip_bfloat16*)&kq[i];
    const __hip_bfloat16* vp = (const __hip_bfloat16*)&vq[i];
#pragma unroll
    for (int j = 0; j < 8; ++j) {
      const int c = c0 + i * 8 + j;
      const int off = c * 136 + ((c >> 5) & 1) * 32 + rr;
      ekT[off] = __float2bfloat16(__expf(__bfloat162float(kp[j])));
      vfT[off] = vp[j];
    }
  }
  __syncthreads();

  // ---- MFMA: part[d][e] over K=128 rows ----
  const int w = t >> 6, l = t & 63;
  const int lr = l & 15, hk = l >> 4;
  f32x4 acc[4];
#pragma unroll
  for (int n = 0; n < 4; ++n) acc[n] = (f32x4){0.f, 0.f, 0.f, 0.f};

  const int arow = w * 16 + lr;
  const int abase = arow * 136 + ((arow >> 5) & 1) * 32 + hk * 8;
#pragma unroll
  for (int ks = 0; ks < 4; ++ks) {
    bf16x8 af = *(const bf16x8*)(ekT + abase + ks * 32);
#pragma unroll
    for (int n = 0; n < 4; ++n) {
      const int brow = n * 16 + lr;
      bf16x8 bf = *(const bf16x8*)(vfT + brow * 136 + ((brow >> 5) & 1) * 32 +
                                   hk * 8 + ks * 32);
      acc[n] =
          __builtin_amdgcn_mfma_f32_16x16x32_bf16(af, bf, acc[n], 0, 0, 0);
    }
  }

  float* pb = part + ((size_t)bh * 32 + s) * 4096;
#pragma unroll
  for (int n = 0; n < 4; ++n)
#pragma unroll
    for (int j = 0; j < 4; ++j)
      pb[(w * 16 + hk * 4 + j) * 64 + n * 16 + lr] = acc[n][j];

  // ---- den partial from the same bf16 ekT ----
  if ((t & 3) == 0) {
    const int d = t >> 2;
    const int dbase = d * 136 + ((d >> 5) & 1) * 32;
    float sden = 0.f;
#pragma unroll
    for (int q8 = 0; q8 < 16; ++q8) {
      bf16x8 e8 = *(const bf16x8*)(ekT + dbase + q8 * 8);
      const __hip_bfloat16* ep = (const __hip_bfloat16*)&e8;
#pragma unroll
      for (int j = 0; j < 8; ++j) sden += __bfloat162float(ep[j]);
    }
    den[((size_t)bh * 32 + s) * 64 + d] = sden;
  }
}

// ---------------------------------------------------------------------------
// ctxb[bh][d][e] = bf16( (sum_s part) / (sum_s den[d]) ); grid (64,4) x 256
// ---------------------------------------------------------------------------
__global__ __launch_bounds__(256) void ctx_reduce_k(
    const float* __restrict__ part, const float* __restrict__ den,
    __hip_bfloat16* __restrict__ ctxb) {
  const int bh = blockIdx.x, q = blockIdx.y, t = threadIdx.x;
  const int idx = q * 1024 + t * 4;
  const int d = idx >> 6;
  float sden = 0.f;
  for (int s = 0; s < 32; ++s) sden += den[((size_t)bh * 32 + s) * 64 + d];
  float4 sv = {0.f, 0.f, 0.f, 0.f};
  const float* pb = part + (size_t)bh * 32 * 4096 + idx;
  for (int s = 0; s < 32; ++s) {
    float4 v = *(const float4*)(pb + (size_t)s * 4096);
    sv.x += v.x; sv.y += v.y; sv.z += v.z; sv.w += v.w;
  }
  const float di = 1.0f / sden;
  __hip_bfloat16 ob[4] __attribute__((aligned(8)));
  ob[0] = __float2bfloat16(sv.x * di);
  ob[1] = __float2bfloat16(sv.y * di);
  ob[2] = __float2bfloat16(sv.z * di);
  ob[3] = __float2bfloat16(sv.w * di);
  *(int2*)&ctxb[(size_t)bh * 4096 + idx] = *(const int2*)ob;
}

// ---------------------------------------------------------------------------
// WfT[b][n][k] = sum_e ctx[b][h(k)][k&63][e] * Wo[h*64+e][n]  (bf16, MFMA)
// grid (64 bh, 16 n-chunks) x 256 (4 waves x 16 rows)
// ---------------------------------------------------------------------------
__global__ __launch_bounds__(256) void wfuse_k(
    const __hip_bfloat16* __restrict__ WT,
    const __hip_bfloat16* __restrict__ ctxb, __hip_bfloat16* __restrict__ WfT) {
  const int bh = blockIdx.x;
  const int b = bh >> 4, h = bh & 15;
  const int t = threadIdx.x, w = t >> 6, l = t & 63;
  const int n1 = blockIdx.y * 64 + w * 16;
  const int lr = l & 15, hk = l >> 4;

  f32x4 acc[4];
#pragma unroll
  for (int n = 0; n < 4; ++n) acc[n] = (f32x4){0.f, 0.f, 0.f, 0.f};

  const __hip_bfloat16* Abase =
      WT + (size_t)(3072 + n1 + lr) * 1024 + h * 64 + hk * 8;
  const __hip_bfloat16* Bbase = ctxb + (size_t)bh * 4096 + hk * 8;

#pragma unroll
  for (int kk2 = 0; kk2 < 2; ++kk2) {
    bf16x8 af = *(const bf16x8*)(Abase + kk2 * 32);
#pragma unroll
    for (int n = 0; n < 4; ++n) {
      bf16x8 bf = *(const bf16x8*)(Bbase + (n * 16 + lr) * 64 + kk2 * 32);
      acc[n] = __builtin_amdgcn_mfma_f32_16x16x32_bf16(af, bf, acc[n], 0, 0, 0);
    }
  }

  __hip_bfloat16* W0 = WfT + ((size_t)b << 20) + (size_t)(n1 + hk * 4) * 1024 +
                       h * 64 + lr;
#pragma unroll
  for (int n = 0; n < 4; ++n)
#pragma unroll
    for (int j = 0; j < 4; ++j)
      W0[(size_t)j * 1024 + n * 16] = __float2bfloat16(acc[n][j]);
}

// ---------------------------------------------------------------------------
extern "C" void kernel_launch(void* const* d_in, const int* in_sizes, int n_in,
                              void* d_out, int out_size, void* d_ws,
                              size_t ws_size, hipStream_t stream) {
  const float* x = (const float*)d_in[0];
  const float* Wq = (const float*)d_in[1];
  const float* Wk = (const float*)d_in[2];
  const float* Wv = (const float*)d_in[3];
  const float* Wo = (const float*)d_in[4];
  const float* bo = (const float*)d_in[5];
  float* out = (float*)d_out;

  // ws: qkv bf16 [16384][3072] (96MB) | WT bf16 [4096][1024] (8MB)
  //     | den f32 (512KB) | ctxb bf16 (512KB) | WfT bf16 4x[1024][1024] (8MB)
  char* ws = (char*)d_ws;
  __hip_bfloat16* qkv = (__hip_bfloat16*)ws;
  __hip_bfloat16* WT = (__hip_bfloat16*)(ws + 100663296ull);
  float* den = (float*)(ws + 100663296ull + 8388608ull);
  __hip_bfloat16* ctxb =
      (__hip_bfloat16*)(ws + 100663296ull + 8388608ull + 524288ull);
  __hip_bfloat16* WfT =
      (__hip_bfloat16*)(ws + 100663296ull + 8388608ull + 1048576ull);
  // d_out doubles as scratch, fully overwritten by the final GEMM:
  //   [0,32MB) xb bf16; [32,64MB) part f32 [64][32][4096]
  __hip_bfloat16* xb = (__hip_bfloat16*)d_out;
  float* part = (float*)((char*)d_out + 33554432ull);

  const dim3 blk(256);

  xconv_k<<<dim3(NROWS * 1024 / 8 / 256), blk, 0, stream>>>(x, xb);
  wconv_k<<<dim3(16, 16, 4), blk, 0, stream>>>(Wq, Wk, Wv, Wo, WT);

  // QKV projection: [16384,3072] = xb @ [Wq|Wk|Wv]
  mgemm3_k<0, 0><<<dim3(768), dim3(512), 0, stream>>>(xb, 1024, WT, nullptr,
                                                      qkv, 3072, 12);

  // fused q-softmax + context partials (MFMA)
  ctxq_k<<<dim3(64, 32), blk, 0, stream>>>(qkv, part, den);
  ctx_reduce_k<<<dim3(64, 4), blk, 0, stream>>>(part, den, ctxb);
  wfuse_k<<<dim3(64, 16), blk, 0, stream>>>(WT, ctxb, WfT);

  // out = qs @ Wfused[b] + bo
  mgemm3_k<1, 1><<<dim3(256), dim3(512), 0, stream>>>(qkv, 3072, WfT, bo, out,
                                                      1024, 4);
}